// Round 22
// baseline (202.810 us; speedup 1.0000x reference)
//
#include <hip/hip_runtime.h>
#include <math.h>

#define BB 4
#define SS 2048
#define DD 1024
#define HH 16
#define DHH 64
#define NBH 64
#define SCC 0.18033688011112042f   // 0.125 * log2(e)

typedef __attribute__((ext_vector_type(8))) short bf16x8;
typedef __attribute__((ext_vector_type(8))) unsigned short ushort8;
typedef __attribute__((ext_vector_type(4))) float f32x4;
typedef __attribute__((ext_vector_type(16))) float f32x16;
typedef __attribute__((ext_vector_type(2))) unsigned u32x2;
typedef unsigned short u16;

__device__ inline u16 f2bf(float x) {
    union { float f; unsigned u; } v; v.f = x;
    unsigned r = v.u + 0x7fffu + ((v.u >> 16) & 1u);   // RNE
    return (u16)(r >> 16);
}
__device__ inline float bf2f(u16 x) {
    union { unsigned u; float f; } v; v.u = ((unsigned)x) << 16;
    return v.f;
}

__device__ inline void gload16(const u16* g, u16* l) {
    __builtin_amdgcn_global_load_lds(
        (const __attribute__((address_space(1))) unsigned int*)(const void*)g,
        (__attribute__((address_space(3))) unsigned int*)(void*)l, 16, 0, 0);
}

// SSA-safe cross-half primitives (builtin returns BOTH results — no aliasing).
__device__ inline void plswap(unsigned& a, unsigned& b) {
    u32x2 r = __builtin_amdgcn_permlane32_swap(a, b, false, false);
    a = r[0]; b = r[1];
}
__device__ inline float xhalf_max(float x) {
    u32x2 r = __builtin_amdgcn_permlane32_swap(
        __float_as_uint(x), __float_as_uint(x), false, false);
    return fmaxf(__uint_as_float(r[0]), __uint_as_float(r[1]));
}
__device__ inline float xhalf_sum(float x) {
    u32x2 r = __builtin_amdgcn_permlane32_swap(
        __float_as_uint(x), __float_as_uint(x), false, false);
    return __uint_as_float(r[0]) + __uint_as_float(r[1]);
}

// ---------------------------------------------------------------------------
// fp32 -> bf16 conversion, ALL tensors in one launch.
// ---------------------------------------------------------------------------
__global__ __launch_bounds__(256)
void cvt_all(const float* __restrict__ q, const float* __restrict__ k,
             const float* __restrict__ v,
             const float* __restrict__ wq, const float* __restrict__ wk,
             const float* __restrict__ wv, const float* __restrict__ wo,
             const int* __restrict__ vlens,
             u16* __restrict__ oq, u16* __restrict__ ok, u16* __restrict__ ov,
             u16* __restrict__ owq, u16* __restrict__ owk,
             u16* __restrict__ owv, u16* __restrict__ owo)
{
    const int id = blockIdx.x;
    const float* s; u16* d; size_t i0;
    if (id < 12288) {
        const int y = id >> 12, xx = id & 4095;
        i0 = (size_t)xx * 2048;
        if (y == 0) { s = q; d = oq; }
        else if (y == 1) { s = k; d = ok; }
        else { s = v; d = ov; }
        if (y != 0) {
            const int b  = (int)(i0 >> 21);
            const int s0 = (int)(i0 >> 10) & (SS - 1);
            const int c32 = ((vlens[b] + 31) >> 5) << 5;
            if (s0 >= c32) return;
        }
    } else {
        const int r = id - 12288;
        const int y = r >> 9, xx = r & 511;
        i0 = (size_t)xx * 2048;
        if (y == 0) { s = wq; d = owq; }
        else if (y == 1) { s = wk; d = owk; }
        else if (y == 2) { s = wv; d = owv; }
        else { s = wo; d = owo; }
    }
    const size_t i = i0 + (size_t)threadIdx.x * 8;
    const float4 a = *(const float4*)(s + i);
    const float4 c = *(const float4*)(s + i + 4);
    ushort8 r;
    r[0] = f2bf(a.x); r[1] = f2bf(a.y); r[2] = f2bf(a.z); r[3] = f2bf(a.w);
    r[4] = f2bf(c.x); r[5] = f2bf(c.y); r[6] = f2bf(c.z); r[7] = f2bf(c.w);
    *(ushort8*)(d + i) = r;
}

// ---------------------------------------------------------------------------
// V (BH,S,DH) -> Vt (BH,DH,S) transpose, bf16. Tiles past ceil32(vlen) skipped.
// ---------------------------------------------------------------------------
__global__ __launch_bounds__(256)
void transpose_v(const u16* __restrict__ Vp, const int* __restrict__ vlens,
                 u16* __restrict__ Vt)
{
    __shared__ __align__(16) u16 tile[64][72];
    const int t = threadIdx.x;
    const int s0 = blockIdx.x * 64;
    const int bh = blockIdx.y;
    const int b  = bh >> 4;
    const int c32 = ((vlens[b] + 31) >> 5) << 5;
    if (s0 >= c32) return;
    const u16* src = Vp + ((size_t)bh * SS + s0) * DHH;
    const int r = t >> 2, d0 = (t & 3) * 16;
    *(ushort8*)&tile[r][d0]     = *(const ushort8*)(src + r * DHH + d0);
    *(ushort8*)&tile[r][d0 + 8] = *(const ushort8*)(src + r * DHH + d0 + 8);
    __syncthreads();
    const int d = t >> 2, sl = (t & 3) * 16;
    ushort8 o0, o1;
    #pragma unroll
    for (int j = 0; j < 8; ++j) o0[j] = tile[sl + j][d];
    #pragma unroll
    for (int j = 0; j < 8; ++j) o1[j] = tile[sl + 8 + j][d];
    u16* dst = Vt + ((size_t)bh * DHH + d) * SS + s0 + sl;
    *(ushort8*)dst       = o0;
    *(ushort8*)(dst + 8) = o1;
}

// ---------------------------------------------------------------------------
// Shared GEMM core v2: C = A (Mx1024) @ B^T, 128x128 tile, BK=64, both-sides
// XOR-swizzled LDS (proven round 18: 8-way -> 2-way conflicts, barriers /2).
// ---------------------------------------------------------------------------
template<int OUT_MODE>
__device__ __forceinline__
void gemm_core(const u16* __restrict__ A, const u16* __restrict__ B,
               void* __restrict__ Cv, int m0, int n0, u16* As, u16* Bs)
{
    const int t = threadIdx.x;
    const int w = t >> 6, l = t & 63;
    const int lm = l & 15, lg = l >> 4;
    const int wr = w >> 1, wc = w & 1;

    const int lrow = l >> 3;             // 0..7
    const int lcb  = (l & 7) ^ lrow;     // pre-swizzled global col-block
    const u16* ga = A + (size_t)(m0 + w * 32 + lrow) * DD + lcb * 8;
    const u16* gb = B + (size_t)(n0 + w * 32 + lrow) * DD + lcb * 8;
    u16* lA = &As[w * 2048];
    u16* lB = &Bs[w * 2048];

    f32x4 acc[4][4];
    #pragma unroll
    for (int i = 0; i < 4; ++i)
        #pragma unroll
        for (int j = 0; j < 4; ++j)
            acc[i][j] = (f32x4){0.f, 0.f, 0.f, 0.f};

    for (int k0 = 0; k0 < DD; k0 += 64) {
        __syncthreads();
        gload16(ga + k0,           lA);
        gload16(ga + k0 +  8 * DD, lA + 512);
        gload16(ga + k0 + 16 * DD, lA + 1024);
        gload16(ga + k0 + 24 * DD, lA + 1536);
        gload16(gb + k0,           lB);
        gload16(gb + k0 +  8 * DD, lB + 512);
        gload16(gb + k0 + 16 * DD, lB + 1024);
        gload16(gb + k0 + 24 * DD, lB + 1536);
        __syncthreads();
        #pragma unroll
        for (int kk = 0; kk < 2; ++kk) {
            bf16x8 af[4], bfr[4];
            #pragma unroll
            for (int mi = 0; mi < 4; ++mi) {
                const int R = wr * 64 + mi * 16 + lm;
                af[mi] = *(const bf16x8*)&As[R * 64 + (((kk * 4 + lg) ^ (R & 7)) * 8)];
            }
            #pragma unroll
            for (int ni = 0; ni < 4; ++ni) {
                const int R = wc * 64 + ni * 16 + lm;
                bfr[ni] = *(const bf16x8*)&Bs[R * 64 + (((kk * 4 + lg) ^ (R & 7)) * 8)];
            }
            #pragma unroll
            for (int mi = 0; mi < 4; ++mi)
                #pragma unroll
                for (int ni = 0; ni < 4; ++ni)
                    acc[mi][ni] = __builtin_amdgcn_mfma_f32_16x16x32_bf16(
                        af[mi], bfr[ni], acc[mi][ni], 0, 0, 0);
        }
    }

    #pragma unroll
    for (int mi = 0; mi < 4; ++mi) {
        #pragma unroll
        for (int r = 0; r < 4; ++r) {
            const int m = m0 + wr * 64 + mi * 16 + lg * 4 + r;
            if (OUT_MODE == 0) {
                float* C = (float*)Cv;
                #pragma unroll
                for (int ni = 0; ni < 4; ++ni)
                    C[(size_t)m * DD + n0 + wc * 64 + ni * 16 + lm] = acc[mi][ni][r];
            } else {
                u16* C = (u16*)Cv;
                const int b = m >> 11, s = m & (SS - 1);
                #pragma unroll
                for (int ni = 0; ni < 4; ++ni) {
                    const int n = n0 + wc * 64 + ni * 16 + lm;
                    const int h = n >> 6, dh = n & 63;
                    C[(((size_t)b * HH + h) * SS + s) * DHH + dh] = f2bf(acc[mi][ni][r]);
                }
            }
        }
    }
}

__global__ __launch_bounds__(256)
void gemm_qkv(const u16* __restrict__ Xq, const u16* __restrict__ Xk,
              const u16* __restrict__ Xv,
              const u16* __restrict__ Wqb, const u16* __restrict__ Wkb,
              const u16* __restrict__ Wvb,
              u16* __restrict__ Qo, u16* __restrict__ Ko, u16* __restrict__ Vo,
              const int* __restrict__ vlens)
{
    __shared__ __align__(16) u16 As[128 * 64];
    __shared__ __align__(16) u16 Bs[128 * 64];
    const int z = blockIdx.z;
    const int m0 = blockIdx.y * 128, n0 = blockIdx.x * 128;
    const u16* A; const u16* B; u16* C;
    if (z == 0) { A = Xq; B = Wqb; C = Qo; }
    else if (z == 1) { A = Xk; B = Wkb; C = Ko; }
    else { A = Xv; B = Wvb; C = Vo; }
    if (z != 0) {
        const int b = m0 >> 11, s0 = m0 & (SS - 1);
        const int c32 = ((vlens[b] + 31) >> 5) << 5;
        if (s0 >= c32) return;
    }
    gemm_core<1>(A, B, (void*)C, m0, n0, As, Bs);
}

__global__ __launch_bounds__(256)
void gemm_out(const u16* __restrict__ A, const u16* __restrict__ B,
              float* __restrict__ C)
{
    __shared__ __align__(16) u16 As[128 * 64];
    __shared__ __align__(16) u16 Bs[128 * 64];
    gemm_core<0>(A, B, (void*)C, blockIdx.y * 128, blockIdx.x * 128, As, Bs);
}

// ---------------------------------------------------------------------------
// MFMA flash attention v18 = v15 (dual-stream ILP + cross-block KV-split)
// with the register budget RESTORED: __launch_bounds__(64,2) keeps the
// proven 96-VGPR dense codegen (v15's (64,3) squeezed to 84 and serialized
// the chains). Grid 4096 one-wave blocks vs residency ~2-3/SIMD ->
// 1000-2000 queued blocks = genuine refill, drain amortized; per-wave
// critical path halves for vlen>1024. Combine kernel merges split halves.
//   S^T = mfma(A=K, B=Q)     -> lane owns one q-row (q = lane&31) of scores
//   O^T = mfma(A=V^T, B=P^T) -> lane owns one q-row of output
// ---------------------------------------------------------------------------
#define LOADK4(coff) do {                                                      \
    const u16* kp_ = kb + (size_t)(coff) * DHH;                                \
    kf[0] = *(const bf16x8*)kp_;                                               \
    kf[1] = *(const bf16x8*)(kp_ + 16);                                        \
    kf[2] = *(const bf16x8*)(kp_ + 32);                                        \
    kf[3] = *(const bf16x8*)(kp_ + 48);                                        \
} while (0)

#define LOADV4(coff) do {                                                      \
    const u16* vp_ = vb + (coff);                                              \
    va[0] = *(const bf16x8*)vp_;                                               \
    va[1] = *(const bf16x8*)(vp_ + 16);                                        \
    va[2] = *(const bf16x8*)(vp_ + (size_t)32 * SS);                           \
    va[3] = *(const bf16x8*)(vp_ + (size_t)32 * SS + 16);                      \
} while (0)

__global__ __launch_bounds__(64, 2)
void flash_mfma18(const u16* __restrict__ Qp, const u16* __restrict__ Kp,
                  const u16* __restrict__ Vt, const int* __restrict__ vlens,
                  u16* __restrict__ AO, u16* __restrict__ Op1,
                  float2* __restrict__ Mlp)
{
    const int l = threadIdx.x;
    const int l31 = l & 31, hi = l >> 5;
    // XCD-aware decode; halves of one (bh,qpair) are blockIdx-adjacent mod 8.
    const int x = blockIdx.x;
    const int xcd  = x & 7;
    const int rest = x >> 3;                 // 0..511
    const int half = rest & 1;
    const int idx  = rest >> 1;              // 0..255
    const int bh   = xcd + ((idx >> 5) << 3);
    const int qpair = idx & 31;              // 0..31
    const int b = bh >> 4, h = bh & 15;
    const int q0 = qpair * 64;               // stream A: q0, stream B: q0+32
    const int vlen = vlens[b];
    const int split = vlen > 1024;
    if (!split && half) return;
    const int ntb  = (vlen + 31) >> 5;
    const int ntb2 = (ntb + 1) >> 1;
    const int tb0 = split ? (half ? ntb2 : 0) : 0;
    const int tb1 = split ? (half ? ntb : ntb2) : ntb;

    const u16* qbA = Qp + ((size_t)bh * SS + q0 + l31) * DHH + hi * 8;
    bf16x8 qvA[4], qvB[4];
    qvA[0] = *(const bf16x8*)qbA;
    qvA[1] = *(const bf16x8*)(qbA + 16);
    qvA[2] = *(const bf16x8*)(qbA + 32);
    qvA[3] = *(const bf16x8*)(qbA + 48);
    const u16* qbB = qbA + (size_t)32 * DHH;
    qvB[0] = *(const bf16x8*)qbB;
    qvB[1] = *(const bf16x8*)(qbB + 16);
    qvB[2] = *(const bf16x8*)(qbB + 32);
    qvB[3] = *(const bf16x8*)(qbB + 48);

    const u16* kb = Kp + ((size_t)bh * SS + l31) * DHH + hi * 8;
    const u16* vb = Vt + ((size_t)bh * DHH + l31) * SS + hi * 8;

    bf16x8 kf[4], va[4];
    LOADK4(tb0 * 32);
    LOADV4(tb0 * 32);

    f32x16 oA0, oA1, oB0, oB1;
    #pragma unroll
    for (int r = 0; r < 16; ++r) { oA0[r] = 0.f; oA1[r] = 0.f; oB0[r] = 0.f; oB1[r] = 0.f; }
    float mA = -3e38f, lA = 0.f, mB = -3e38f, lB = 0.f;

    for (int tt = tb0; tt < tb1; ++tt) {
        const int c0 = tt * 32;
        // --- QK^T, two independent accumulator chains interleaved
        f32x16 zA, zB;
        #pragma unroll
        for (int r = 0; r < 16; ++r) { zA[r] = 0.f; zB[r] = 0.f; }
        __builtin_amdgcn_s_setprio(1);
        zA = __builtin_amdgcn_mfma_f32_32x32x16_bf16(kf[0], qvA[0], zA, 0, 0, 0);
        zB = __builtin_amdgcn_mfma_f32_32x32x16_bf16(kf[0], qvB[0], zB, 0, 0, 0);
        zA = __builtin_amdgcn_mfma_f32_32x32x16_bf16(kf[1], qvA[1], zA, 0, 0, 0);
        zB = __builtin_amdgcn_mfma_f32_32x32x16_bf16(kf[1], qvB[1], zB, 0, 0, 0);
        zA = __builtin_amdgcn_mfma_f32_32x32x16_bf16(kf[2], qvA[2], zA, 0, 0, 0);
        zB = __builtin_amdgcn_mfma_f32_32x32x16_bf16(kf[2], qvB[2], zB, 0, 0, 0);
        zA = __builtin_amdgcn_mfma_f32_32x32x16_bf16(kf[3], qvA[3], zA, 0, 0, 0);
        zB = __builtin_amdgcn_mfma_f32_32x32x16_bf16(kf[3], qvB[3], zB, 0, 0, 0);
        __builtin_amdgcn_s_setprio(0);
        if (tt + 1 < tb1) LOADK4(c0 + 32);

        // --- mask (last tile only; wave-uniform branch; same cols both streams)
        if (vlen - c0 < 32) {
            #pragma unroll
            for (int r = 0; r < 16; ++r) {
                const int kvl = (r & 3) + 8 * (r >> 2) + 4 * hi;
                if (c0 + kvl >= vlen) { zA[r] = -3e38f; zB[r] = -3e38f; }
            }
        }

        // --- row max, both streams (independent chains)
        float mxA = fmaxf(zA[0], zA[1]);
        float mxB = fmaxf(zB[0], zB[1]);
        #pragma unroll
        for (int r = 2; r < 16; ++r) { mxA = fmaxf(mxA, zA[r]); mxB = fmaxf(mxB, zB[r]); }
        mxA = xhalf_max(mxA);
        mxB = xhalf_max(mxB);

        // --- defer-max per stream (rare, wave-uniform)
        float corrA = 1.f, corrB = 1.f;
        if (!__all(mxA <= mA + 64.0f)) {
            const float mold = mA;
            mA = fmaxf(mA, mxA);
            corrA = exp2f((mold - mA) * SCC);
            #pragma unroll
            for (int r = 0; r < 16; ++r) { oA0[r] *= corrA; oA1[r] *= corrA; }
        }
        if (!__all(mxB <= mB + 64.0f)) {
            const float mold = mB;
            mB = fmaxf(mB, mxB);
            corrB = exp2f((mold - mB) * SCC);
            #pragma unroll
            for (int r = 0; r < 16; ++r) { oB0[r] *= corrB; oB1[r] *= corrB; }
        }

        // --- p = exp2(z*SCC - m*SCC), both streams
        const float mscA = mA * SCC, mscB = mB * SCC;
        float tsA = 0.f, tsB = 0.f;
        #pragma unroll
        for (int r = 0; r < 16; ++r) {
            const float pA = exp2f(__builtin_fmaf(zA[r], SCC, -mscA));
            const float pB = exp2f(__builtin_fmaf(zB[r], SCC, -mscB));
            zA[r] = pA; zB[r] = pB;
            tsA += pA; tsB += pB;
        }
        tsA = xhalf_sum(tsA);
        tsB = xhalf_sum(tsB);
        lA = lA * corrA + tsA;
        lB = lB * corrB + tsB;

        // --- pack both streams to bf16 B-fragments
        unsigned a0, a1, a2, a3, a4, a5, a6, a7;
        unsigned b0, b1, b2, b3, b4, b5, b6, b7;
        asm("v_cvt_pk_bf16_f32 %0, %1, %2" : "=v"(a0) : "v"(zA[0]),  "v"(zA[1]));
        asm("v_cvt_pk_bf16_f32 %0, %1, %2" : "=v"(a1) : "v"(zA[2]),  "v"(zA[3]));
        asm("v_cvt_pk_bf16_f32 %0, %1, %2" : "=v"(a2) : "v"(zA[4]),  "v"(zA[5]));
        asm("v_cvt_pk_bf16_f32 %0, %1, %2" : "=v"(a3) : "v"(zA[6]),  "v"(zA[7]));
        asm("v_cvt_pk_bf16_f32 %0, %1, %2" : "=v"(a4) : "v"(zA[8]),  "v"(zA[9]));
        asm("v_cvt_pk_bf16_f32 %0, %1, %2" : "=v"(a5) : "v"(zA[10]), "v"(zA[11]));
        asm("v_cvt_pk_bf16_f32 %0, %1, %2" : "=v"(a6) : "v"(zA[12]), "v"(zA[13]));
        asm("v_cvt_pk_bf16_f32 %0, %1, %2" : "=v"(a7) : "v"(zA[14]), "v"(zA[15]));
        asm("v_cvt_pk_bf16_f32 %0, %1, %2" : "=v"(b0) : "v"(zB[0]),  "v"(zB[1]));
        asm("v_cvt_pk_bf16_f32 %0, %1, %2" : "=v"(b1) : "v"(zB[2]),  "v"(zB[3]));
        asm("v_cvt_pk_bf16_f32 %0, %1, %2" : "=v"(b2) : "v"(zB[4]),  "v"(zB[5]));
        asm("v_cvt_pk_bf16_f32 %0, %1, %2" : "=v"(b3) : "v"(zB[6]),  "v"(zB[7]));
        asm("v_cvt_pk_bf16_f32 %0, %1, %2" : "=v"(b4) : "v"(zB[8]),  "v"(zB[9]));
        asm("v_cvt_pk_bf16_f32 %0, %1, %2" : "=v"(b5) : "v"(zB[10]), "v"(zB[11]));
        asm("v_cvt_pk_bf16_f32 %0, %1, %2" : "=v"(b6) : "v"(zB[12]), "v"(zB[13]));
        asm("v_cvt_pk_bf16_f32 %0, %1, %2" : "=v"(b7) : "v"(zB[14]), "v"(zB[15]));

        plswap(a0, a2); plswap(a1, a3); plswap(a4, a6); plswap(a5, a7);
        plswap(b0, b2); plswap(b1, b3); plswap(b4, b6); plswap(b5, b7);

        bf16x8 pA0, pA1, pB0, pB1;
        ((unsigned*)&pA0)[0] = a0; ((unsigned*)&pA0)[1] = a1;
        ((unsigned*)&pA0)[2] = a2; ((unsigned*)&pA0)[3] = a3;
        ((unsigned*)&pA1)[0] = a4; ((unsigned*)&pA1)[1] = a5;
        ((unsigned*)&pA1)[2] = a6; ((unsigned*)&pA1)[3] = a7;
        ((unsigned*)&pB0)[0] = b0; ((unsigned*)&pB0)[1] = b1;
        ((unsigned*)&pB0)[2] = b2; ((unsigned*)&pB0)[3] = b3;
        ((unsigned*)&pB1)[0] = b4; ((unsigned*)&pB1)[1] = b5;
        ((unsigned*)&pB1)[2] = b6; ((unsigned*)&pB1)[3] = b7;

        // --- PV: 4 independent accumulator chains of length 2
        __builtin_amdgcn_s_setprio(1);
        oA0 = __builtin_amdgcn_mfma_f32_32x32x16_bf16(va[0], pA0, oA0, 0, 0, 0);
        oB0 = __builtin_amdgcn_mfma_f32_32x32x16_bf16(va[0], pB0, oB0, 0, 0, 0);
        oA1 = __builtin_amdgcn_mfma_f32_32x32x16_bf16(va[2], pA0, oA1, 0, 0, 0);
        oB1 = __builtin_amdgcn_mfma_f32_32x32x16_bf16(va[2], pB0, oB1, 0, 0, 0);
        oA0 = __builtin_amdgcn_mfma_f32_32x32x16_bf16(va[1], pA1, oA0, 0, 0, 0);
        oB0 = __builtin_amdgcn_mfma_f32_32x32x16_bf16(va[1], pB1, oB0, 0, 0, 0);
        oA1 = __builtin_amdgcn_mfma_f32_32x32x16_bf16(va[3], pA1, oA1, 0, 0, 0);
        oB1 = __builtin_amdgcn_mfma_f32_32x32x16_bf16(va[3], pB1, oB1, 0, 0, 0);
        __builtin_amdgcn_s_setprio(0);
        if (tt + 1 < tb1) LOADV4(c0 + 32);
    }

    // --- epilogue: unsplit -> final AO; split -> per-half o/l + (m,l) sideband
    const float invA = 1.f / lA;
    const float invB = 1.f / lB;
    u16* base = (split && half) ? Op1 : AO;
    u16* obA = base + ((size_t)b * SS + q0 + l31) * DD + h * DHH + hi * 4;
    u16* obB = obA + (size_t)32 * DD;
    if (split && hi == 0) {
        float2 mlA; mlA.x = mA; mlA.y = lA;
        float2 mlB; mlB.x = mB; mlB.y = lB;
        Mlp[(size_t)half * NBH * SS + (size_t)bh * SS + q0 + l31]      = mlA;
        Mlp[(size_t)half * NBH * SS + (size_t)bh * SS + q0 + 32 + l31] = mlB;
    }
    #pragma unroll
    for (int rq = 0; rq < 4; ++rq) {
        #pragma unroll
        for (int rp = 0; rp < 2; ++rp) {
            const int r = rq * 4 + rp * 2;
            unsigned w0, w1, w2, w3;
            asm("v_cvt_pk_bf16_f32 %0, %1, %2" : "=v"(w0)
                : "v"(oA0[r] * invA), "v"(oA0[r + 1] * invA));
            asm("v_cvt_pk_bf16_f32 %0, %1, %2" : "=v"(w1)
                : "v"(oA1[r] * invA), "v"(oA1[r + 1] * invA));
            asm("v_cvt_pk_bf16_f32 %0, %1, %2" : "=v"(w2)
                : "v"(oB0[r] * invB), "v"(oB0[r + 1] * invB));
            asm("v_cvt_pk_bf16_f32 %0, %1, %2" : "=v"(w3)
                : "v"(oB1[r] * invB), "v"(oB1[r + 1] * invB));
            *(unsigned*)(obA + rq * 8 + rp * 2)      = w0;
            *(unsigned*)(obA + 32 + rq * 8 + rp * 2) = w1;
            *(unsigned*)(obB + rq * 8 + rp * 2)      = w2;
            *(unsigned*)(obB + 32 + rq * 8 + rp * 2) = w3;
        }
    }
}

// ---------------------------------------------------------------------------
// Merge split rows: out = (w0*o0 + w1*o1)/(w0+w1), w_i = exp2((m_i-M)*SCC)*l_i.
// ---------------------------------------------------------------------------
__global__ __launch_bounds__(256)
void combine_halves(const int* __restrict__ vlens,
                    const float2* __restrict__ Mlp,
                    const u16* __restrict__ Op1, u16* __restrict__ AO)
{
    const int tid = blockIdx.x * 256 + threadIdx.x;   // 0 .. 131071
    const int h = tid & 15;
    const int rowq = tid >> 4;                        // b*2048 + q
    const int b = rowq >> 11, q = rowq & 2047;
    if (vlens[b] <= 1024) return;
    const int bh = b * 16 + h;
    const float2 ml0 = Mlp[(size_t)bh * SS + q];
    const float2 ml1 = Mlp[(size_t)NBH * SS + (size_t)bh * SS + q];
    const float M  = fmaxf(ml0.x, ml1.x);
    const float e0 = exp2f((ml0.x - M) * SCC) * ml0.y;
    const float e1 = exp2f((ml1.x - M) * SCC) * ml1.y;
    const float inv = 1.f / (e0 + e1);
    const float a0 = e0 * inv, a1 = e1 * inv;
    u16* ao = AO + ((size_t)b * SS + q) * DD + h * DHH;
    const u16* p1 = Op1 + ((size_t)b * SS + q) * DD + h * DHH;
    #pragma unroll
    for (int i = 0; i < 8; ++i) {
        const ushort8 x0 = *(const ushort8*)(ao + i * 8);
        const ushort8 x1 = *(const ushort8*)(p1 + i * 8);
        ushort8 o;
        #pragma unroll
        for (int j = 0; j < 8; ++j)
            o[j] = f2bf(a0 * bf2f(x0[j]) + a1 * bf2f(x1[j]));
        *(ushort8*)(ao + i * 8) = o;
    }
}

extern "C" void kernel_launch(void* const* d_in, const int* in_sizes, int n_in,
                              void* d_out, int out_size, void* d_ws, size_t ws_size,
                              hipStream_t stream) {
    const float* queries = (const float*)d_in[0];
    const float* keys    = (const float*)d_in[1];
    const float* values  = (const float*)d_in[2];
    const int*   vlens   = (const int*)d_in[3];
    const float* Wq      = (const float*)d_in[4];
    const float* Wk      = (const float*)d_in[5];
    const float* Wv      = (const float*)d_in[6];
    const float* Wo      = (const float*)d_in[7];

    u16* ws = (u16*)d_ws;
    const size_t NX = (size_t)BB * SS * DD;   // 8,388,608
    const size_t NW = (size_t)DD * DD;        // 1,048,576
    u16* Xq  = ws;
    u16* Xk  = Xq  + NX;
    u16* Xv  = Xk  + NX;
    u16* Wqb = Xv  + NX;
    u16* Wkb = Wqb + NW;
    u16* Wvb = Wkb + NW;
    u16* Wob = Wvb + NW;
    u16* Qp  = Wob + NW;
    u16* Kp  = Qp  + NX;
    u16* Vp  = Kp  + NX;
    u16* Vtb = Vp  + NX;
    u16* AO  = Xq;                 // alias: Xq dead after the Q projection
    u16* Op1 = Xk;                 // alias: Xk dead after gemm_qkv (NX u16)
    float2* Mlp = (float2*)Xv;     // alias: Xv dead after gemm_qkv (4 MB)

    cvt_all<<<dim3(14336), 256, 0, stream>>>(queries, keys, values,
                                             Wq, Wk, Wv, Wo, vlens,
                                             Xq, Xk, Xv, Wqb, Wkb, Wvb, Wob);

    gemm_qkv<<<dim3(DD / 128, (BB * SS) / 128, 3), 256, 0, stream>>>(
        Xq, Xk, Xv, Wqb, Wkb, Wvb, Qp, Kp, Vp, vlens);

    transpose_v<<<dim3(SS / 64, NBH), 256, 0, stream>>>(Vp, vlens, Vtb);
    flash_mfma18<<<dim3(4096), 64, 0, stream>>>(Qp, Kp, Vtb, vlens, AO, Op1, Mlp);
    combine_halves<<<dim3(512), 256, 0, stream>>>(vlens, Mlp, Op1, AO);

    gemm_out<<<dim3(DD / 128, (BB * SS) / 128), 256, 0, stream>>>(AO, Wob, (float*)d_out);
}

// Round 23
// 191.603 us; speedup vs baseline: 1.0585x; 1.0585x over previous
//
#include <hip/hip_runtime.h>
#include <math.h>

#define BB 4
#define SS 2048
#define DD 1024
#define HH 16
#define DHH 64
#define NBH 64
#define SCC 0.18033688011112042f   // 0.125 * log2(e)

typedef __attribute__((ext_vector_type(8))) short bf16x8;
typedef __attribute__((ext_vector_type(8))) unsigned short ushort8;
typedef __attribute__((ext_vector_type(4))) float f32x4;
typedef __attribute__((ext_vector_type(16))) float f32x16;
typedef __attribute__((ext_vector_type(2))) unsigned u32x2;
typedef unsigned short u16;

__device__ inline u16 f2bf(float x) {
    union { float f; unsigned u; } v; v.f = x;
    unsigned r = v.u + 0x7fffu + ((v.u >> 16) & 1u);   // RNE
    return (u16)(r >> 16);
}

__device__ inline void gload16(const u16* g, u16* l) {
    __builtin_amdgcn_global_load_lds(
        (const __attribute__((address_space(1))) unsigned int*)(const void*)g,
        (__attribute__((address_space(3))) unsigned int*)(void*)l, 16, 0, 0);
}

// SSA-safe cross-half primitives (builtin returns BOTH results — no aliasing).
__device__ inline void plswap(unsigned& a, unsigned& b) {
    u32x2 r = __builtin_amdgcn_permlane32_swap(a, b, false, false);
    a = r[0]; b = r[1];
}
__device__ inline float xhalf_max(float x) {
    u32x2 r = __builtin_amdgcn_permlane32_swap(
        __float_as_uint(x), __float_as_uint(x), false, false);
    return fmaxf(__uint_as_float(r[0]), __uint_as_float(r[1]));
}
__device__ inline float xhalf_sum(float x) {
    u32x2 r = __builtin_amdgcn_permlane32_swap(
        __float_as_uint(x), __float_as_uint(x), false, false);
    return __uint_as_float(r[0]) + __uint_as_float(r[1]);
}

// ---------------------------------------------------------------------------
// fp32 -> bf16 conversion, ALL tensors in one launch.
// ---------------------------------------------------------------------------
__global__ __launch_bounds__(256)
void cvt_all(const float* __restrict__ q, const float* __restrict__ k,
             const float* __restrict__ v,
             const float* __restrict__ wq, const float* __restrict__ wk,
             const float* __restrict__ wv, const float* __restrict__ wo,
             const int* __restrict__ vlens,
             u16* __restrict__ oq, u16* __restrict__ ok, u16* __restrict__ ov,
             u16* __restrict__ owq, u16* __restrict__ owk,
             u16* __restrict__ owv, u16* __restrict__ owo)
{
    const int id = blockIdx.x;
    const float* s; u16* d; size_t i0;
    if (id < 12288) {
        const int y = id >> 12, xx = id & 4095;
        i0 = (size_t)xx * 2048;
        if (y == 0) { s = q; d = oq; }
        else if (y == 1) { s = k; d = ok; }
        else { s = v; d = ov; }
        if (y != 0) {
            const int b  = (int)(i0 >> 21);
            const int s0 = (int)(i0 >> 10) & (SS - 1);
            const int c32 = ((vlens[b] + 31) >> 5) << 5;
            if (s0 >= c32) return;
        }
    } else {
        const int r = id - 12288;
        const int y = r >> 9, xx = r & 511;
        i0 = (size_t)xx * 2048;
        if (y == 0) { s = wq; d = owq; }
        else if (y == 1) { s = wk; d = owk; }
        else if (y == 2) { s = wv; d = owv; }
        else { s = wo; d = owo; }
    }
    const size_t i = i0 + (size_t)threadIdx.x * 8;
    const float4 a = *(const float4*)(s + i);
    const float4 c = *(const float4*)(s + i + 4);
    ushort8 r;
    r[0] = f2bf(a.x); r[1] = f2bf(a.y); r[2] = f2bf(a.z); r[3] = f2bf(a.w);
    r[4] = f2bf(c.x); r[5] = f2bf(c.y); r[6] = f2bf(c.z); r[7] = f2bf(c.w);
    *(ushort8*)(d + i) = r;
}

// ---------------------------------------------------------------------------
// V (BH,S,DH) -> Vt (BH,DH,S) transpose, bf16. Tiles past ceil32(vlen) skipped.
// ---------------------------------------------------------------------------
__global__ __launch_bounds__(256)
void transpose_v(const u16* __restrict__ Vp, const int* __restrict__ vlens,
                 u16* __restrict__ Vt)
{
    __shared__ __align__(16) u16 tile[64][72];
    const int t = threadIdx.x;
    const int s0 = blockIdx.x * 64;
    const int bh = blockIdx.y;
    const int b  = bh >> 4;
    const int c32 = ((vlens[b] + 31) >> 5) << 5;
    if (s0 >= c32) return;
    const u16* src = Vp + ((size_t)bh * SS + s0) * DHH;
    const int r = t >> 2, d0 = (t & 3) * 16;
    *(ushort8*)&tile[r][d0]     = *(const ushort8*)(src + r * DHH + d0);
    *(ushort8*)&tile[r][d0 + 8] = *(const ushort8*)(src + r * DHH + d0 + 8);
    __syncthreads();
    const int d = t >> 2, sl = (t & 3) * 16;
    ushort8 o0, o1;
    #pragma unroll
    for (int j = 0; j < 8; ++j) o0[j] = tile[sl + j][d];
    #pragma unroll
    for (int j = 0; j < 8; ++j) o1[j] = tile[sl + 8 + j][d];
    u16* dst = Vt + ((size_t)bh * DHH + d) * SS + s0 + sl;
    *(ushort8*)dst       = o0;
    *(ushort8*)(dst + 8) = o1;
}

// ---------------------------------------------------------------------------
// Shared GEMM core v2: C = A (Mx1024) @ B^T, 128x128 tile, BK=64 (halves the
// barrier/drain count of the 2-phase loop), both-sides XOR-swizzled LDS
// (rule #21: linear global_load_lds dest + pre-swizzled GLOBAL source col
// (l&7)^(l>>3) + same XOR on the ds_read index). Read conflicts drop from
// 8-way (old [128][32] linear) to 2-way (free).
// OUT_MODE 0: fp32 row-major. OUT_MODE 1: bf16 head-split (B,H,S,DH).
// ---------------------------------------------------------------------------
template<int OUT_MODE>
__device__ __forceinline__
void gemm_core(const u16* __restrict__ A, const u16* __restrict__ B,
               void* __restrict__ Cv, int m0, int n0, u16* As, u16* Bs)
{
    const int t = threadIdx.x;
    const int w = t >> 6, l = t & 63;
    const int lm = l & 15, lg = l >> 4;
    const int wr = w >> 1, wc = w & 1;

    const int lrow = l >> 3;             // 0..7
    const int lcb  = (l & 7) ^ lrow;     // pre-swizzled global col-block
    const u16* ga = A + (size_t)(m0 + w * 32 + lrow) * DD + lcb * 8;
    const u16* gb = B + (size_t)(n0 + w * 32 + lrow) * DD + lcb * 8;
    u16* lA = &As[w * 2048];
    u16* lB = &Bs[w * 2048];

    f32x4 acc[4][4];
    #pragma unroll
    for (int i = 0; i < 4; ++i)
        #pragma unroll
        for (int j = 0; j < 4; ++j)
            acc[i][j] = (f32x4){0.f, 0.f, 0.f, 0.f};

    for (int k0 = 0; k0 < DD; k0 += 64) {
        __syncthreads();
        gload16(ga + k0,           lA);
        gload16(ga + k0 +  8 * DD, lA + 512);
        gload16(ga + k0 + 16 * DD, lA + 1024);
        gload16(ga + k0 + 24 * DD, lA + 1536);
        gload16(gb + k0,           lB);
        gload16(gb + k0 +  8 * DD, lB + 512);
        gload16(gb + k0 + 16 * DD, lB + 1024);
        gload16(gb + k0 + 24 * DD, lB + 1536);
        __syncthreads();
        #pragma unroll
        for (int kk = 0; kk < 2; ++kk) {
            bf16x8 af[4], bfr[4];
            #pragma unroll
            for (int mi = 0; mi < 4; ++mi) {
                const int R = wr * 64 + mi * 16 + lm;
                af[mi] = *(const bf16x8*)&As[R * 64 + (((kk * 4 + lg) ^ (R & 7)) * 8)];
            }
            #pragma unroll
            for (int ni = 0; ni < 4; ++ni) {
                const int R = wc * 64 + ni * 16 + lm;
                bfr[ni] = *(const bf16x8*)&Bs[R * 64 + (((kk * 4 + lg) ^ (R & 7)) * 8)];
            }
            #pragma unroll
            for (int mi = 0; mi < 4; ++mi)
                #pragma unroll
                for (int ni = 0; ni < 4; ++ni)
                    acc[mi][ni] = __builtin_amdgcn_mfma_f32_16x16x32_bf16(
                        af[mi], bfr[ni], acc[mi][ni], 0, 0, 0);
        }
    }

    #pragma unroll
    for (int mi = 0; mi < 4; ++mi) {
        #pragma unroll
        for (int r = 0; r < 4; ++r) {
            const int m = m0 + wr * 64 + mi * 16 + lg * 4 + r;
            if (OUT_MODE == 0) {
                float* C = (float*)Cv;
                #pragma unroll
                for (int ni = 0; ni < 4; ++ni)
                    C[(size_t)m * DD + n0 + wc * 64 + ni * 16 + lm] = acc[mi][ni][r];
            } else {
                u16* C = (u16*)Cv;
                const int b = m >> 11, s = m & (SS - 1);
                #pragma unroll
                for (int ni = 0; ni < 4; ++ni) {
                    const int n = n0 + wc * 64 + ni * 16 + lm;
                    const int h = n >> 6, dh = n & 63;
                    C[(((size_t)b * HH + h) * SS + s) * DHH + dh] = f2bf(acc[mi][ni][r]);
                }
            }
        }
    }
}

__global__ __launch_bounds__(256)
void gemm_qkv(const u16* __restrict__ Xq, const u16* __restrict__ Xk,
              const u16* __restrict__ Xv,
              const u16* __restrict__ Wqb, const u16* __restrict__ Wkb,
              const u16* __restrict__ Wvb,
              u16* __restrict__ Qo, u16* __restrict__ Ko, u16* __restrict__ Vo,
              const int* __restrict__ vlens)
{
    __shared__ __align__(16) u16 As[128 * 64];
    __shared__ __align__(16) u16 Bs[128 * 64];
    const int z = blockIdx.z;
    const int m0 = blockIdx.y * 128, n0 = blockIdx.x * 128;
    const u16* A; const u16* B; u16* C;
    if (z == 0) { A = Xq; B = Wqb; C = Qo; }
    else if (z == 1) { A = Xk; B = Wkb; C = Ko; }
    else { A = Xv; B = Wvb; C = Vo; }
    if (z != 0) {
        const int b = m0 >> 11, s0 = m0 & (SS - 1);
        const int c32 = ((vlens[b] + 31) >> 5) << 5;
        if (s0 >= c32) return;
    }
    gemm_core<1>(A, B, (void*)C, m0, n0, As, Bs);
}

__global__ __launch_bounds__(256)
void gemm_out(const u16* __restrict__ A, const u16* __restrict__ B,
              float* __restrict__ C)
{
    __shared__ __align__(16) u16 As[128 * 64];
    __shared__ __align__(16) u16 Bs[128 * 64];
    gemm_core<0>(A, B, (void*)C, blockIdx.y * 128, blockIdx.x * 128, As, Bs);
}

// ---------------------------------------------------------------------------
// MFMA flash attention v13 (byte-exact round-15 winner, 97.7us): dual-stream
// ILP waves — each 1-wave block processes TWO q-tiles (q0, q0+32) of the
// same bh, sharing K/V registers; two independent dependency chains halve
// per-wave stall. Grid 2048 one-wave blocks, XCD swizzle, launch_bounds(64,2).
//   S^T = mfma(A=K, B=Q)     -> lane owns one q-row (q = lane&31) of scores
//   O^T = mfma(A=V^T, B=P^T) -> lane owns one q-row of output
// ---------------------------------------------------------------------------
#define LOADK4(coff) do {                                                      \
    const u16* kp_ = kb + (size_t)(coff) * DHH;                                \
    kf[0] = *(const bf16x8*)kp_;                                               \
    kf[1] = *(const bf16x8*)(kp_ + 16);                                        \
    kf[2] = *(const bf16x8*)(kp_ + 32);                                        \
    kf[3] = *(const bf16x8*)(kp_ + 48);                                        \
} while (0)

#define LOADV4(coff) do {                                                      \
    const u16* vp_ = vb + (coff);                                              \
    va[0] = *(const bf16x8*)vp_;                                               \
    va[1] = *(const bf16x8*)(vp_ + 16);                                        \
    va[2] = *(const bf16x8*)(vp_ + (size_t)32 * SS);                           \
    va[3] = *(const bf16x8*)(vp_ + (size_t)32 * SS + 16);                      \
} while (0)

__global__ __launch_bounds__(64, 2)
void flash_mfma13(const u16* __restrict__ Qp, const u16* __restrict__ Kp,
                  const u16* __restrict__ Vt, const int* __restrict__ vlens,
                  u16* __restrict__ AO)
{
    const int l = threadIdx.x;
    const int l31 = l & 31, hi = l >> 5;
    // XCD-aware decode: xcd = x&7 owns bh with bh%8 == xcd.
    const int x = blockIdx.x;
    const int xcd = x & 7;
    const int idx = x >> 3;                  // 0..255
    const int bh  = xcd + ((idx >> 5) << 3); // bh%8 == xcd
    const int qpair = idx & 31;              // 0..31
    const int b = bh >> 4, h = bh & 15;
    const int q0 = qpair * 64;               // stream A: q0, stream B: q0+32
    const int vlen = vlens[b];
    const int ntb = (vlen + 31) >> 5;

    const u16* qbA = Qp + ((size_t)bh * SS + q0 + l31) * DHH + hi * 8;
    bf16x8 qvA[4], qvB[4];
    qvA[0] = *(const bf16x8*)qbA;
    qvA[1] = *(const bf16x8*)(qbA + 16);
    qvA[2] = *(const bf16x8*)(qbA + 32);
    qvA[3] = *(const bf16x8*)(qbA + 48);
    const u16* qbB = qbA + (size_t)32 * DHH;
    qvB[0] = *(const bf16x8*)qbB;
    qvB[1] = *(const bf16x8*)(qbB + 16);
    qvB[2] = *(const bf16x8*)(qbB + 32);
    qvB[3] = *(const bf16x8*)(qbB + 48);

    const u16* kb = Kp + ((size_t)bh * SS + l31) * DHH + hi * 8;
    const u16* vb = Vt + ((size_t)bh * DHH + l31) * SS + hi * 8;

    bf16x8 kf[4], va[4];
    LOADK4(0);
    LOADV4(0);

    f32x16 oA0, oA1, oB0, oB1;
    #pragma unroll
    for (int r = 0; r < 16; ++r) { oA0[r] = 0.f; oA1[r] = 0.f; oB0[r] = 0.f; oB1[r] = 0.f; }
    float mA = -3e38f, lA = 0.f, mB = -3e38f, lB = 0.f;

    for (int tt = 0; tt < ntb; ++tt) {
        const int c0 = tt * 32;
        // --- QK^T, two independent accumulator chains interleaved
        f32x16 zA, zB;
        #pragma unroll
        for (int r = 0; r < 16; ++r) { zA[r] = 0.f; zB[r] = 0.f; }
        __builtin_amdgcn_s_setprio(1);
        zA = __builtin_amdgcn_mfma_f32_32x32x16_bf16(kf[0], qvA[0], zA, 0, 0, 0);
        zB = __builtin_amdgcn_mfma_f32_32x32x16_bf16(kf[0], qvB[0], zB, 0, 0, 0);
        zA = __builtin_amdgcn_mfma_f32_32x32x16_bf16(kf[1], qvA[1], zA, 0, 0, 0);
        zB = __builtin_amdgcn_mfma_f32_32x32x16_bf16(kf[1], qvB[1], zB, 0, 0, 0);
        zA = __builtin_amdgcn_mfma_f32_32x32x16_bf16(kf[2], qvA[2], zA, 0, 0, 0);
        zB = __builtin_amdgcn_mfma_f32_32x32x16_bf16(kf[2], qvB[2], zB, 0, 0, 0);
        zA = __builtin_amdgcn_mfma_f32_32x32x16_bf16(kf[3], qvA[3], zA, 0, 0, 0);
        zB = __builtin_amdgcn_mfma_f32_32x32x16_bf16(kf[3], qvB[3], zB, 0, 0, 0);
        __builtin_amdgcn_s_setprio(0);
        if (tt + 1 < ntb) LOADK4(c0 + 32);

        // --- mask (last tile only; wave-uniform branch; same cols both streams)
        if (vlen - c0 < 32) {
            #pragma unroll
            for (int r = 0; r < 16; ++r) {
                const int kvl = (r & 3) + 8 * (r >> 2) + 4 * hi;
                if (c0 + kvl >= vlen) { zA[r] = -3e38f; zB[r] = -3e38f; }
            }
        }

        // --- row max, both streams (independent chains)
        float mxA = fmaxf(zA[0], zA[1]);
        float mxB = fmaxf(zB[0], zB[1]);
        #pragma unroll
        for (int r = 2; r < 16; ++r) { mxA = fmaxf(mxA, zA[r]); mxB = fmaxf(mxB, zB[r]); }
        mxA = xhalf_max(mxA);
        mxB = xhalf_max(mxB);

        // --- defer-max per stream (rare, wave-uniform)
        float corrA = 1.f, corrB = 1.f;
        if (!__all(mxA <= mA + 64.0f)) {
            const float mold = mA;
            mA = fmaxf(mA, mxA);
            corrA = exp2f((mold - mA) * SCC);
            #pragma unroll
            for (int r = 0; r < 16; ++r) { oA0[r] *= corrA; oA1[r] *= corrA; }
        }
        if (!__all(mxB <= mB + 64.0f)) {
            const float mold = mB;
            mB = fmaxf(mB, mxB);
            corrB = exp2f((mold - mB) * SCC);
            #pragma unroll
            for (int r = 0; r < 16; ++r) { oB0[r] *= corrB; oB1[r] *= corrB; }
        }

        // --- p = exp2(z*SCC - m*SCC), both streams
        const float mscA = mA * SCC, mscB = mB * SCC;
        float tsA = 0.f, tsB = 0.f;
        #pragma unroll
        for (int r = 0; r < 16; ++r) {
            const float pA = exp2f(__builtin_fmaf(zA[r], SCC, -mscA));
            const float pB = exp2f(__builtin_fmaf(zB[r], SCC, -mscB));
            zA[r] = pA; zB[r] = pB;
            tsA += pA; tsB += pB;
        }
        tsA = xhalf_sum(tsA);
        tsB = xhalf_sum(tsB);
        lA = lA * corrA + tsA;
        lB = lB * corrB + tsB;

        // --- pack both streams to bf16 B-fragments
        unsigned a0, a1, a2, a3, a4, a5, a6, a7;
        unsigned b0, b1, b2, b3, b4, b5, b6, b7;
        asm("v_cvt_pk_bf16_f32 %0, %1, %2" : "=v"(a0) : "v"(zA[0]),  "v"(zA[1]));
        asm("v_cvt_pk_bf16_f32 %0, %1, %2" : "=v"(a1) : "v"(zA[2]),  "v"(zA[3]));
        asm("v_cvt_pk_bf16_f32 %0, %1, %2" : "=v"(a2) : "v"(zA[4]),  "v"(zA[5]));
        asm("v_cvt_pk_bf16_f32 %0, %1, %2" : "=v"(a3) : "v"(zA[6]),  "v"(zA[7]));
        asm("v_cvt_pk_bf16_f32 %0, %1, %2" : "=v"(a4) : "v"(zA[8]),  "v"(zA[9]));
        asm("v_cvt_pk_bf16_f32 %0, %1, %2" : "=v"(a5) : "v"(zA[10]), "v"(zA[11]));
        asm("v_cvt_pk_bf16_f32 %0, %1, %2" : "=v"(a6) : "v"(zA[12]), "v"(zA[13]));
        asm("v_cvt_pk_bf16_f32 %0, %1, %2" : "=v"(a7) : "v"(zA[14]), "v"(zA[15]));
        asm("v_cvt_pk_bf16_f32 %0, %1, %2" : "=v"(b0) : "v"(zB[0]),  "v"(zB[1]));
        asm("v_cvt_pk_bf16_f32 %0, %1, %2" : "=v"(b1) : "v"(zB[2]),  "v"(zB[3]));
        asm("v_cvt_pk_bf16_f32 %0, %1, %2" : "=v"(b2) : "v"(zB[4]),  "v"(zB[5]));
        asm("v_cvt_pk_bf16_f32 %0, %1, %2" : "=v"(b3) : "v"(zB[6]),  "v"(zB[7]));
        asm("v_cvt_pk_bf16_f32 %0, %1, %2" : "=v"(b4) : "v"(zB[8]),  "v"(zB[9]));
        asm("v_cvt_pk_bf16_f32 %0, %1, %2" : "=v"(b5) : "v"(zB[10]), "v"(zB[11]));
        asm("v_cvt_pk_bf16_f32 %0, %1, %2" : "=v"(b6) : "v"(zB[12]), "v"(zB[13]));
        asm("v_cvt_pk_bf16_f32 %0, %1, %2" : "=v"(b7) : "v"(zB[14]), "v"(zB[15]));

        plswap(a0, a2); plswap(a1, a3); plswap(a4, a6); plswap(a5, a7);
        plswap(b0, b2); plswap(b1, b3); plswap(b4, b6); plswap(b5, b7);

        bf16x8 pA0, pA1, pB0, pB1;
        ((unsigned*)&pA0)[0] = a0; ((unsigned*)&pA0)[1] = a1;
        ((unsigned*)&pA0)[2] = a2; ((unsigned*)&pA0)[3] = a3;
        ((unsigned*)&pA1)[0] = a4; ((unsigned*)&pA1)[1] = a5;
        ((unsigned*)&pA1)[2] = a6; ((unsigned*)&pA1)[3] = a7;
        ((unsigned*)&pB0)[0] = b0; ((unsigned*)&pB0)[1] = b1;
        ((unsigned*)&pB0)[2] = b2; ((unsigned*)&pB0)[3] = b3;
        ((unsigned*)&pB1)[0] = b4; ((unsigned*)&pB1)[1] = b5;
        ((unsigned*)&pB1)[2] = b6; ((unsigned*)&pB1)[3] = b7;

        // --- PV: 4 independent accumulator chains of length 2
        __builtin_amdgcn_s_setprio(1);
        oA0 = __builtin_amdgcn_mfma_f32_32x32x16_bf16(va[0], pA0, oA0, 0, 0, 0);
        oB0 = __builtin_amdgcn_mfma_f32_32x32x16_bf16(va[0], pB0, oB0, 0, 0, 0);
        oA1 = __builtin_amdgcn_mfma_f32_32x32x16_bf16(va[2], pA0, oA1, 0, 0, 0);
        oB1 = __builtin_amdgcn_mfma_f32_32x32x16_bf16(va[2], pB0, oB1, 0, 0, 0);
        oA0 = __builtin_amdgcn_mfma_f32_32x32x16_bf16(va[1], pA1, oA0, 0, 0, 0);
        oB0 = __builtin_amdgcn_mfma_f32_32x32x16_bf16(va[1], pB1, oB0, 0, 0, 0);
        oA1 = __builtin_amdgcn_mfma_f32_32x32x16_bf16(va[3], pA1, oA1, 0, 0, 0);
        oB1 = __builtin_amdgcn_mfma_f32_32x32x16_bf16(va[3], pB1, oB1, 0, 0, 0);
        __builtin_amdgcn_s_setprio(0);
        if (tt + 1 < ntb) LOADV4(c0 + 32);
    }

    // --- normalize + write both streams
    const float invA = 1.f / lA;
    const float invB = 1.f / lB;
    u16* obA = AO + ((size_t)b * SS + q0 + l31) * DD + h * DHH + hi * 4;
    u16* obB = obA + (size_t)32 * DD;
    #pragma unroll
    for (int rq = 0; rq < 4; ++rq) {
        #pragma unroll
        for (int rp = 0; rp < 2; ++rp) {
            const int r = rq * 4 + rp * 2;
            unsigned w0, w1, w2, w3;
            asm("v_cvt_pk_bf16_f32 %0, %1, %2" : "=v"(w0)
                : "v"(oA0[r] * invA), "v"(oA0[r + 1] * invA));
            asm("v_cvt_pk_bf16_f32 %0, %1, %2" : "=v"(w1)
                : "v"(oA1[r] * invA), "v"(oA1[r + 1] * invA));
            asm("v_cvt_pk_bf16_f32 %0, %1, %2" : "=v"(w2)
                : "v"(oB0[r] * invB), "v"(oB0[r + 1] * invB));
            asm("v_cvt_pk_bf16_f32 %0, %1, %2" : "=v"(w3)
                : "v"(oB1[r] * invB), "v"(oB1[r + 1] * invB));
            *(unsigned*)(obA + rq * 8 + rp * 2)      = w0;
            *(unsigned*)(obA + 32 + rq * 8 + rp * 2) = w1;
            *(unsigned*)(obB + rq * 8 + rp * 2)      = w2;
            *(unsigned*)(obB + 32 + rq * 8 + rp * 2) = w3;
        }
    }
}

extern "C" void kernel_launch(void* const* d_in, const int* in_sizes, int n_in,
                              void* d_out, int out_size, void* d_ws, size_t ws_size,
                              hipStream_t stream) {
    const float* queries = (const float*)d_in[0];
    const float* keys    = (const float*)d_in[1];
    const float* values  = (const float*)d_in[2];
    const int*   vlens   = (const int*)d_in[3];
    const float* Wq      = (const float*)d_in[4];
    const float* Wk      = (const float*)d_in[5];
    const float* Wv      = (const float*)d_in[6];
    const float* Wo      = (const float*)d_in[7];

    u16* ws = (u16*)d_ws;
    const size_t NX = (size_t)BB * SS * DD;   // 8,388,608
    const size_t NW = (size_t)DD * DD;        // 1,048,576
    u16* Xq  = ws;
    u16* Xk  = Xq  + NX;
    u16* Xv  = Xk  + NX;
    u16* Wqb = Xv  + NX;
    u16* Wkb = Wqb + NW;
    u16* Wvb = Wkb + NW;
    u16* Wob = Wvb + NW;
    u16* Qp  = Wob + NW;
    u16* Kp  = Qp  + NX;
    u16* Vp  = Kp  + NX;
    u16* Vtb = Vp  + NX;
    u16* AO  = Xq;   // alias: Xq dead after the Q projection

    cvt_all<<<dim3(14336), 256, 0, stream>>>(queries, keys, values,
                                             Wq, Wk, Wv, Wo, vlens,
                                             Xq, Xk, Xv, Wqb, Wkb, Wvb, Wob);

    gemm_qkv<<<dim3(DD / 128, (BB * SS) / 128, 3), 256, 0, stream>>>(
        Xq, Xk, Xv, Wqb, Wkb, Wvb, Qp, Kp, Vp, vlens);

    transpose_v<<<dim3(SS / 64, NBH), 256, 0, stream>>>(Vp, vlens, Vtb);
    flash_mfma13<<<dim3(2048), 64, 0, stream>>>(Qp, Kp, Vtb, vlens, AO);

    gemm_out<<<dim3(DD / 128, (BB * SS) / 128), 256, 0, stream>>>(AO, Wob, (float*)d_out);
}